// Round 10
// baseline (308.512 us; speedup 1.0000x reference)
//
#include <hip/hip_runtime.h>
#include <hip/hip_fp16.h>

#define N_TOK 8192
#define DMODEL 1024
#define HDIM 2048
#define NEXP 8
#define NGU (2 * HDIM)               // 4096 interleaved gate/up cols
#define NPAD (N_TOK + NEXP * 256)    // 10240 (expert segments padded to x256)
#define NTILES (NPAD / 256)          // 40 (256-row tiles, GEMM1)
#define NT2 (2 * NTILES)             // 80 (128-row tiles, GEMM2)
#define G1TILES (NTILES * 16)        // 640 GEMM1 tile-blocks
#define CVT_BLKS 128                 // tail blocks folded into GEMM1 dispatch

typedef _Float16 f16;
typedef _Float16 f16x8 __attribute__((ext_vector_type(8)));
typedef float f32x4 __attribute__((ext_vector_type(4)));

#define SBAR() __builtin_amdgcn_sched_barrier(0)
#define BARRIER() do { __builtin_amdgcn_s_barrier(); SBAR(); } while (0)
#define WAIT_LGKM0() do { asm volatile("s_waitcnt lgkmcnt(0)" ::: "memory"); SBAR(); } while (0)
#define WAIT_VM(n)  do { asm volatile("s_waitcnt vmcnt(" #n ")" ::: "memory"); SBAR(); } while (0)

__device__ __forceinline__ void gload16(const void* g, void* l) {
    __builtin_amdgcn_global_load_lds(
        (const __attribute__((address_space(1))) void*)g,
        (__attribute__((address_space(3))) void*)l, 16, 0, 0);
}

__device__ __forceinline__ f16x8 cvt8(const float* src) {
    const float4 a = ((const float4*)src)[0], b = ((const float4*)src)[1];
    f16x8 v;
    v[0] = (f16)a.x; v[1] = (f16)a.y; v[2] = (f16)a.z; v[3] = (f16)a.w;
    v[4] = (f16)b.x; v[5] = (f16)b.y; v[6] = (f16)b.z; v[7] = (f16)b.w;
    return v;
}

// ---- K1: plan (hist + padded segment maps) + perm init ----
__global__ void k_plan(const int* __restrict__ ids, int* __restrict__ cursor,
                       int* __restrict__ tile_map, int* __restrict__ tile_map2,
                       int* __restrict__ perm) {
    __shared__ int hist[NEXP];
    const int tid = threadIdx.x;
    if (tid < NEXP) hist[tid] = 0;
    for (int i = tid; i < NPAD; i += 256) perm[i] = -1;
    __syncthreads();
    for (int t = tid; t < N_TOK; t += 256) atomicAdd(&hist[ids[t]], 1);
    __syncthreads();
    if (tid == 0) {
        int pos = 0, tile = 0;
        for (int e = 0; e < NEXP; ++e) {
            cursor[e] = pos;
            const int nt = (hist[e] + 255) >> 8;
            for (int i = 0; i < nt; ++i) tile_map[tile++] = e;
            pos += nt * 256;
        }
        for (; tile < NTILES; ++tile) tile_map[tile] = -1;
        for (int t = 0; t < NTILES; ++t) {
            tile_map2[2 * t] = tile_map[t];
            tile_map2[2 * t + 1] = tile_map[t];
        }
    }
}

// ---- K2: scatter token indices into padded perm ----
__global__ void k_scatter(const int* __restrict__ ids, int* __restrict__ cursor,
                          int* __restrict__ perm) {
    const int t = blockIdx.x * 256 + threadIdx.x;
    if (t < N_TOK) {
        const int pos = atomicAdd(&cursor[ids[t]], 1);
        perm[pos] = t;
    }
}

// ---- K3: merged prep: gather x rows + gate/up -> interleaved wgu f16 ----
__global__ void k_prep(const float* __restrict__ x, const int* __restrict__ perm,
                       f16* __restrict__ xp, const float* __restrict__ wg,
                       const float* __restrict__ wu, f16* __restrict__ wgu) {
    const int bid = blockIdx.x;
    const int t = threadIdx.x;    // 128 threads x 8 elems = 1024
    if (bid < NPAD) {
        const int tok = perm[bid];
        f16x8 v;
#pragma unroll
        for (int j = 0; j < 8; ++j) v[j] = (f16)0.f;
        if (tok >= 0) v = cvt8(x + (size_t)tok * DMODEL + t * 8);
        *((f16x8*)(xp + (size_t)bid * DMODEL) + t) = v;
    } else {
        const int R = bid - NPAD;                 // 0..NEXP*NGU-1
        const int e = R >> 12, c = R & (NGU - 1);
        const int h = ((c >> 5) << 4) | (c & 15); // col c: bit4 -> up
        const float* src = (((c >> 4) & 1) ? wu : wg) + ((size_t)e * HDIM + h) * DMODEL;
        ((f16x8*)(wgu + (size_t)R * DMODEL))[t] = cvt8(src + t * 8);
    }
}

// ---- fp32 -> f16 plain convert kernel (small-ws fallback for wd) ----
__global__ void k_cvt(const float* __restrict__ src, f16* __restrict__ dst) {
    const size_t i = (size_t)blockIdx.x * 256 + threadIdx.x;
    ((f16x8*)dst)[i] = cvt8(src + i * 8);
}

// ======== GEMM1 core: 256x256 8-phase (round-4/7 exact; best measured) ========
#define GEMM_CORE(NKT_, STRIDE_)                                                      \
    const int tid = threadIdx.x;                                                      \
    const int lane = tid & 63, wid = tid >> 6;                                        \
    const int wm = wid >> 2, wn = wid & 3;                                            \
    const int lrow = lane & 15, lk = lane >> 4;                                       \
    const int scol = (lane & 7) ^ (lane >> 3);                                        \
    const int xs0 = ((lk) ^ (lrow & 7)) * 16;                                         \
    const int xs1 = ((4 + lk) ^ (lrow & 7)) * 16;                                     \
    f32x4 acc[8][4] = {};                                                             \
    auto stage = [&](int h, int kt2) {                                                \
        const f16* base = (h < 2) ? (asrc + (size_t)(h * 128) * STRIDE_)              \
                                  : (bsrc + (size_t)((h - 2) * 128) * STRIDE_);       \
        char* dst = smem + ((kt2 & 1) * 4 + h) * 16384 + wid * 1024;                  \
        const int kb = kt2 * 64;                                                      \
        _Pragma("unroll")                                                             \
        for (int pass = 0; pass < 2; ++pass) {                                        \
            const int row = pass * 64 + wid * 8 + (lane >> 3);                        \
            gload16(base + (size_t)row * STRIDE_ + kb + scol * 8, dst + pass * 8192); \
        }                                                                             \
    };                                                                                \
    stage(0, 0); stage(1, 0); stage(2, 0); stage(3, 0);                               \
    stage(2, 1); stage(3, 1);                                                         \
    WAIT_VM(4);                                                                       \
    BARRIER();                                                                        \
    f16x8 b[4][2];                                                                    \
    _Pragma("unroll 1")                                                               \
    for (int kt = 0; kt < NKT_; ++kt) {                                               \
        char* bufA = smem + ((kt & 1) * 4 + wm) * 16384;                              \
        char* bufB = smem + ((kt & 1) * 4 + 2 + (wn >> 1)) * 16384;                   \
        const int brow = (wn & 1) * 64;                                               \
        _Pragma("unroll")                                                             \
        for (int q = 0; q < 4; ++q) {                                                 \
            f16x8 a[2][2];                                                            \
            _Pragma("unroll")                                                         \
            for (int mi = 0; mi < 2; ++mi) {                                          \
                const int r = q * 32 + mi * 16 + lrow;                                \
                a[mi][0] = *(const f16x8*)(bufA + r * 128 + xs0);                     \
                a[mi][1] = *(const f16x8*)(bufA + r * 128 + xs1);                     \
            }                                                                         \
            if (q == 0) {                                                             \
                _Pragma("unroll")                                                     \
                for (int n = 0; n < 4; ++n) {                                         \
                    const int r = brow + n * 16 + lrow;                               \
                    b[n][0] = *(const f16x8*)(bufB + r * 128 + xs0);                  \
                    b[n][1] = *(const f16x8*)(bufB + r * 128 + xs1);                  \
                }                                                                     \
            }                                                                         \
            if (q == 0 && kt + 1 < NKT_) stage(0, kt + 1);                            \
            if (q == 1 && kt + 1 < NKT_) stage(1, kt + 1);                            \
            if (q == 2 && kt + 2 < NKT_) stage(2, kt + 2);                            \
            if (q == 3) {                                                             \
                if (kt + 2 < NKT_) { WAIT_VM(2); stage(3, kt + 2); }                  \
                else { WAIT_VM(0); }                                                  \
            }                                                                         \
            BARRIER();                                                                \
            WAIT_LGKM0();                                                             \
            __builtin_amdgcn_s_setprio(1);                                            \
            _Pragma("unroll")                                                         \
            for (int mi = 0; mi < 2; ++mi)                                            \
                _Pragma("unroll")                                                     \
                for (int n = 0; n < 4; ++n) {                                         \
                    acc[q * 2 + mi][n] = __builtin_amdgcn_mfma_f32_16x16x32_f16(      \
                        a[mi][0], b[n][0], acc[q * 2 + mi][n], 0, 0, 0);              \
                    acc[q * 2 + mi][n] = __builtin_amdgcn_mfma_f32_16x16x32_f16(      \
                        a[mi][1], b[n][1], acc[q * 2 + mi][n], 0, 0, 0);              \
                }                                                                     \
            __builtin_amdgcn_s_setprio(0);                                            \
            BARRIER();                                                                \
        }                                                                             \
    }

// ---- GEMM1 (xp @ wgu^T) + SwiGLU -> hidden; tail blocks convert wd -> wd16 ----
__global__ __launch_bounds__(512, 2) void k_gemm1(
    const f16* __restrict__ xp, const f16* __restrict__ wgu,
    const int* __restrict__ tile_map, f16* __restrict__ hidden,
    const float* __restrict__ wd, f16* __restrict__ wd16) {
    __shared__ char smem[131072];
    const int bid = blockIdx.x;
    if (bid >= G1TILES) {
        // tail-fold: wd fp32 -> f16 on CUs idle in GEMM1's last dispatch round
        const int cb = bid - G1TILES;                       // 0..127
        const int t = threadIdx.x;                          // 512
#pragma unroll 1
        for (int s = 0; s < 32; ++s) {
            const size_t i = ((size_t)s * CVT_BLKS + cb) * 512 + t;  // 8-elem chunks
            ((f16x8*)wd16)[i] = cvt8(wd + i * 8);
        }
        return;
    }
    const int ct = bid & 15, rt = bid >> 4;   // ct-fast
    const int e = tile_map[rt];
    if (e < 0) return;
    const int rbase = rt * 256, cbase = ct * 256;
    const f16* asrc = xp + (size_t)rbase * DMODEL;
    const f16* bsrc = wgu + (size_t)e * NGU * DMODEL + (size_t)cbase * DMODEL;

    GEMM_CORE(16, DMODEL)

    // epilogue: pair (gate,up) frags -> silu(g)*u -> hidden f16
#pragma unroll
    for (int mf = 0; mf < 8; ++mf) {
#pragma unroll
        for (int pair = 0; pair < 2; ++pair) {
            const int ng = pair * 2, nu = ng + 1;
            const int cblock = cbase + wn * 64 + ng * 16;   // bit4==0: gate
            const int h = ((cblock >> 5) << 4) + lrow;
#pragma unroll
            for (int r = 0; r < 4; ++r) {
                const int row = rbase + wm * 128 + mf * 16 + lk * 4 + r;
                const float gg = acc[mf][ng][r], uu = acc[mf][nu][r];
                const float hv = gg / (1.f + __expf(-gg)) * uu;
                hidden[(size_t)row * HDIM + h] = (f16)hv;
            }
        }
    }
}

// ======== GEMM2: 128x128, 4 waves, 32KB LDS (3 blocks/CU) ========
// A (hidden) via gload_lds 2-slot ring; B (wd16) DIRECT L2->reg: ct==XCD
// (blockIdx%8==ct) pins each XCD's B panel (~0.5-1MB) in its L2.
// Per kt: [issue A(kt+1) 4 gloads] vm(4)=drain A(kt)+B(kt) -> barrier ->
// ds_read A(kt) -> lgkm0 -> 32 MFMA(B regs) -> reload B(kt+1) 8 dwordx4 ->
// barrier. Wave FIFO at vm(4): [A(kt)4][B(kt)8][A(kt+1)4] -> keeps A(kt+1).
__global__ __launch_bounds__(256, 3) void k_gemm2(
    const f16* __restrict__ hidden, const f16* __restrict__ wd16,
    const int* __restrict__ tile_map2, const int* __restrict__ perm,
    float* __restrict__ out) {
    const int ct = blockIdx.x, rt = blockIdx.y;   // grid (8, 80); linear%8 = ct
    const int e = tile_map2[rt];
    if (e < 0) return;
    const int tid = threadIdx.x;
    const int lane = tid & 63, wid = tid >> 6;    // 4 waves
    const int wm = wid >> 1, wn = wid & 1;
    const int lrow = lane & 15, lk = lane >> 4;
    const int rbase = rt * 128, cbase = ct * 128;
    const f16* asrc = hidden + (size_t)rbase * HDIM;

    __shared__ char smem[32768];   // A dbuf 2 x 16KB
    const int scol = (lane & 7) ^ (lane >> 3);

    // B fragment pointers: col = cbase + wn*64 + n*16 + lrow; k = ks*32 + lk*8
    const f16* bp[4][2];
#pragma unroll
    for (int n = 0; n < 4; ++n)
#pragma unroll
        for (int ks = 0; ks < 2; ++ks)
            bp[n][ks] = wd16 + ((size_t)e * DMODEL + cbase + wn * 64 + n * 16 + lrow) * HDIM
                      + ks * 32 + lk * 8;

    f16x8 breg[4][2];
    auto loadB = [&](int kt2) {
#pragma unroll
        for (int n = 0; n < 4; ++n)
#pragma unroll
            for (int ks = 0; ks < 2; ++ks)
                asm volatile("global_load_dwordx4 %0, %1, off"
                             : "=v"(breg[n][ks])
                             : "v"(bp[n][ks] + (size_t)kt2 * 64)
                             : "memory");
    };
    auto stageA2 = [&](int kt2) {   // 4 gload16 into slot kt2&1
        char* dst = smem + (kt2 & 1) * 16384;
        const int kb = kt2 * 64;
#pragma unroll
        for (int i = 0; i < 4; ++i) {
            const int chunk = wid * 4 + i;            // 16 chunks x 1KB (8 rows)
            const int row = chunk * 8 + (lane >> 3);
            gload16(asrc + (size_t)row * HDIM + kb + scol * 8, dst + chunk * 1024);
        }
    };

    int off_a[4][2];
#pragma unroll
    for (int f = 0; f < 4; ++f) {
        const int ra = wm * 64 + f * 16 + lrow;
#pragma unroll
        for (int kk = 0; kk < 2; ++kk)
            off_a[f][kk] = ra * 128 + (((kk * 4 + lk) ^ (ra & 7)) * 16);
    }

    f32x4 acc[4][4] = {};
    // prologue: B(0) regs + A(0) LDS, full drain
    loadB(0);
    stageA2(0);
    WAIT_VM(0);
    BARRIER();

#pragma unroll 1
    for (int kt = 0; kt < 32; ++kt) {
        if (kt + 1 < 32) { stageA2(kt + 1); WAIT_VM(4); }
        else { WAIT_VM(0); }
        BARRIER();                 // A(kt) resident for all waves; B(kt) in regs
        char* bA = smem + (kt & 1) * 16384;
        f16x8 a[4][2];
#pragma unroll
        for (int f = 0; f < 4; ++f)
#pragma unroll
            for (int kk = 0; kk < 2; ++kk)
                a[f][kk] = *(const f16x8*)(bA + off_a[f][kk]);
        WAIT_LGKM0();
        __builtin_amdgcn_s_setprio(1);
#pragma unroll
        for (int m = 0; m < 4; ++m)
#pragma unroll
            for (int n = 0; n < 4; ++n) {
                acc[m][n] = __builtin_amdgcn_mfma_f32_16x16x32_f16(a[m][0], breg[n][0], acc[m][n], 0, 0, 0);
                acc[m][n] = __builtin_amdgcn_mfma_f32_16x16x32_f16(a[m][1], breg[n][1], acc[m][n], 0, 0, 0);
            }
        __builtin_amdgcn_s_setprio(0);
        if (kt + 1 < 32) loadB(kt + 1);   // consume-then-reload (WAR: compiler orders)
        BARRIER();                 // A(kt) reads done before next overwrite
    }

    // epilogue: direct scatter to token rows (fp32)
#pragma unroll
    for (int mf = 0; mf < 4; ++mf) {
        int toks[4];
#pragma unroll
        for (int r = 0; r < 4; ++r)
            toks[r] = perm[rbase + wm * 64 + mf * 16 + lk * 4 + r];
#pragma unroll
        for (int n = 0; n < 4; ++n) {
            const int col = cbase + wn * 64 + n * 16 + lrow;
#pragma unroll
            for (int r = 0; r < 4; ++r)
                if (toks[r] >= 0) out[(size_t)toks[r] * DMODEL + col] = acc[mf][n][r];
        }
    }
}

extern "C" void kernel_launch(void* const* d_in, const int* in_sizes, int n_in,
                              void* d_out, int out_size, void* d_ws, size_t ws_size,
                              hipStream_t stream) {
    const float* x = (const float*)d_in[0];
    const float* wg = (const float*)d_in[1];
    const float* wu = (const float*)d_in[2];
    const float* wd = (const float*)d_in[3];
    const int* ids = (const int*)d_in[4];
    float* out = (float*)d_out;

    char* ws = (char*)d_ws;
    int* cursor = (int*)ws;
    int* tile_map = (int*)(ws + 64);
    int* tile_map2 = (int*)(ws + 512);
    int* perm = (int*)(ws + 4096);
    const size_t XP_OFF = 65536;
    const size_t XP_BYTES = (size_t)NPAD * DMODEL * 2;          // 21.0 MB
    const size_t HID_OFF = XP_OFF + XP_BYTES;
    const size_t HID_BYTES = (size_t)NPAD * HDIM * 2;           // 41.9 MB
    const size_t WGU_OFF = HID_OFF + HID_BYTES;
    const size_t WGU_BYTES = (size_t)NEXP * NGU * DMODEL * 2;   // 67.1 MB
    const size_t WD_OFF = WGU_OFF + WGU_BYTES;
    const size_t WD_BYTES = (size_t)NEXP * DMODEL * HDIM * 2;   // 33.6 MB
    const bool big_ws = ws_size >= WD_OFF + WD_BYTES;           // ~163.7 MB

    f16* xp = (f16*)(ws + XP_OFF);
    f16* hidden = (f16*)(ws + HID_OFF);
    f16* wgu16 = (f16*)(ws + WGU_OFF);
    f16* wd16 = big_ws ? (f16*)(ws + WD_OFF) : (f16*)(ws + WGU_OFF);

    k_plan<<<1, 256, 0, stream>>>(ids, cursor, tile_map, tile_map2, perm);
    k_scatter<<<N_TOK / 256, 256, 0, stream>>>(ids, cursor, perm);
    k_prep<<<NPAD + NEXP * NGU, 128, 0, stream>>>(x, perm, xp, wg, wu, wgu16);
    if (big_ws) {
        k_gemm1<<<G1TILES + CVT_BLKS, 512, 0, stream>>>(xp, wgu16, tile_map, hidden, wd, wd16);
    } else {
        k_gemm1<<<G1TILES, 512, 0, stream>>>(xp, wgu16, tile_map, hidden, wd, wd16);
        k_cvt<<<8192, 256, 0, stream>>>(wd, wd16);
    }
    k_gemm2<<<dim3(8, NT2), 256, 0, stream>>>(hidden, wd16, tile_map2, perm, out);
}

// Round 11
// 255.886 us; speedup vs baseline: 1.2057x; 1.2057x over previous
//
#include <hip/hip_runtime.h>
#include <hip/hip_fp16.h>

#define N_TOK 8192
#define DMODEL 1024
#define HDIM 2048
#define NEXP 8
#define NGU (2 * HDIM)               // 4096 interleaved gate/up cols
#define NPAD (N_TOK + NEXP * 256)    // 10240 (expert segments padded to x256)
#define NTILES (NPAD / 256)          // 40 (256-row tiles, GEMM1)
#define NT64 (4 * NTILES)            // 160 (64-row tiles, GEMM2)
#define G1TILES (NTILES * 16)        // 640 GEMM1 tile-blocks
#define CVT_BLKS 128                 // tail blocks folded into GEMM1 dispatch

typedef _Float16 f16;
typedef _Float16 f16x8 __attribute__((ext_vector_type(8)));
typedef float f32x4 __attribute__((ext_vector_type(4)));

#define SBAR() __builtin_amdgcn_sched_barrier(0)
#define BARRIER() do { __builtin_amdgcn_s_barrier(); SBAR(); } while (0)
#define WAIT_LGKM0() do { asm volatile("s_waitcnt lgkmcnt(0)" ::: "memory"); SBAR(); } while (0)
#define WAIT_VM(n)  do { asm volatile("s_waitcnt vmcnt(" #n ")" ::: "memory"); SBAR(); } while (0)

__device__ __forceinline__ void gload16(const void* g, void* l) {
    __builtin_amdgcn_global_load_lds(
        (const __attribute__((address_space(1))) void*)g,
        (__attribute__((address_space(3))) void*)l, 16, 0, 0);
}

__device__ __forceinline__ f16x8 cvt8(const float* src) {
    const float4 a = ((const float4*)src)[0], b = ((const float4*)src)[1];
    f16x8 v;
    v[0] = (f16)a.x; v[1] = (f16)a.y; v[2] = (f16)a.z; v[3] = (f16)a.w;
    v[4] = (f16)b.x; v[5] = (f16)b.y; v[6] = (f16)b.z; v[7] = (f16)b.w;
    return v;
}

// ---- K1: plan (hist + padded segment maps) + perm init ----
__global__ void k_plan(const int* __restrict__ ids, int* __restrict__ cursor,
                       int* __restrict__ tile_map, int* __restrict__ tile_map64,
                       int* __restrict__ perm) {
    __shared__ int hist[NEXP];
    const int tid = threadIdx.x;
    if (tid < NEXP) hist[tid] = 0;
    for (int i = tid; i < NPAD; i += 256) perm[i] = -1;
    __syncthreads();
    for (int t = tid; t < N_TOK; t += 256) atomicAdd(&hist[ids[t]], 1);
    __syncthreads();
    if (tid == 0) {
        int pos = 0, tile = 0;
        for (int e = 0; e < NEXP; ++e) {
            cursor[e] = pos;
            const int nt = (hist[e] + 255) >> 8;
            for (int i = 0; i < nt; ++i) tile_map[tile++] = e;
            pos += nt * 256;
        }
        for (; tile < NTILES; ++tile) tile_map[tile] = -1;
        for (int t = 0; t < NTILES; ++t)
            for (int j = 0; j < 4; ++j) tile_map64[4 * t + j] = tile_map[t];
    }
}

// ---- K2: scatter token indices into padded perm ----
__global__ void k_scatter(const int* __restrict__ ids, int* __restrict__ cursor,
                          int* __restrict__ perm) {
    const int t = blockIdx.x * 256 + threadIdx.x;
    if (t < N_TOK) {
        const int pos = atomicAdd(&cursor[ids[t]], 1);
        perm[pos] = t;
    }
}

// ---- K3: merged prep: gather x rows + gate/up -> interleaved wgu f16 ----
__global__ void k_prep(const float* __restrict__ x, const int* __restrict__ perm,
                       f16* __restrict__ xp, const float* __restrict__ wg,
                       const float* __restrict__ wu, f16* __restrict__ wgu) {
    const int bid = blockIdx.x;
    const int t = threadIdx.x;    // 128 threads x 8 elems = 1024
    if (bid < NPAD) {
        const int tok = perm[bid];
        f16x8 v;
#pragma unroll
        for (int j = 0; j < 8; ++j) v[j] = (f16)0.f;
        if (tok >= 0) v = cvt8(x + (size_t)tok * DMODEL + t * 8);
        *((f16x8*)(xp + (size_t)bid * DMODEL) + t) = v;
    } else {
        const int R = bid - NPAD;                 // 0..NEXP*NGU-1
        const int e = R >> 12, c = R & (NGU - 1);
        const int h = ((c >> 5) << 4) | (c & 15); // col c: bit4 -> up
        const float* src = (((c >> 4) & 1) ? wu : wg) + ((size_t)e * HDIM + h) * DMODEL;
        ((f16x8*)(wgu + (size_t)R * DMODEL))[t] = cvt8(src + t * 8);
    }
}

// ---- fp32 -> f16 plain convert kernel (small-ws fallback for wd) ----
__global__ void k_cvt(const float* __restrict__ src, f16* __restrict__ dst) {
    const size_t i = (size_t)blockIdx.x * 256 + threadIdx.x;
    ((f16x8*)dst)[i] = cvt8(src + i * 8);
}

// ======== GEMM1 core: 256x256 8-phase (round-4/7 exact; best measured) ========
#define GEMM_CORE(NKT_, STRIDE_)                                                      \
    const int tid = threadIdx.x;                                                      \
    const int lane = tid & 63, wid = tid >> 6;                                        \
    const int wm = wid >> 2, wn = wid & 3;                                            \
    const int lrow = lane & 15, lk = lane >> 4;                                       \
    const int scol = (lane & 7) ^ (lane >> 3);                                        \
    const int xs0 = ((lk) ^ (lrow & 7)) * 16;                                         \
    const int xs1 = ((4 + lk) ^ (lrow & 7)) * 16;                                     \
    f32x4 acc[8][4] = {};                                                             \
    auto stage = [&](int h, int kt2) {                                                \
        const f16* base = (h < 2) ? (asrc + (size_t)(h * 128) * STRIDE_)              \
                                  : (bsrc + (size_t)((h - 2) * 128) * STRIDE_);       \
        char* dst = smem + ((kt2 & 1) * 4 + h) * 16384 + wid * 1024;                  \
        const int kb = kt2 * 64;                                                      \
        _Pragma("unroll")                                                             \
        for (int pass = 0; pass < 2; ++pass) {                                        \
            const int row = pass * 64 + wid * 8 + (lane >> 3);                        \
            gload16(base + (size_t)row * STRIDE_ + kb + scol * 8, dst + pass * 8192); \
        }                                                                             \
    };                                                                                \
    stage(0, 0); stage(1, 0); stage(2, 0); stage(3, 0);                               \
    stage(2, 1); stage(3, 1);                                                         \
    WAIT_VM(4);                                                                       \
    BARRIER();                                                                        \
    f16x8 b[4][2];                                                                    \
    _Pragma("unroll 1")                                                               \
    for (int kt = 0; kt < NKT_; ++kt) {                                               \
        char* bufA = smem + ((kt & 1) * 4 + wm) * 16384;                              \
        char* bufB = smem + ((kt & 1) * 4 + 2 + (wn >> 1)) * 16384;                   \
        const int brow = (wn & 1) * 64;                                               \
        _Pragma("unroll")                                                             \
        for (int q = 0; q < 4; ++q) {                                                 \
            f16x8 a[2][2];                                                            \
            _Pragma("unroll")                                                         \
            for (int mi = 0; mi < 2; ++mi) {                                          \
                const int r = q * 32 + mi * 16 + lrow;                                \
                a[mi][0] = *(const f16x8*)(bufA + r * 128 + xs0);                     \
                a[mi][1] = *(const f16x8*)(bufA + r * 128 + xs1);                     \
            }                                                                         \
            if (q == 0) {                                                             \
                _Pragma("unroll")                                                     \
                for (int n = 0; n < 4; ++n) {                                         \
                    const int r = brow + n * 16 + lrow;                               \
                    b[n][0] = *(const f16x8*)(bufB + r * 128 + xs0);                  \
                    b[n][1] = *(const f16x8*)(bufB + r * 128 + xs1);                  \
                }                                                                     \
            }                                                                         \
            if (q == 0 && kt + 1 < NKT_) stage(0, kt + 1);                            \
            if (q == 1 && kt + 1 < NKT_) stage(1, kt + 1);                            \
            if (q == 2 && kt + 2 < NKT_) stage(2, kt + 2);                            \
            if (q == 3) {                                                             \
                if (kt + 2 < NKT_) { WAIT_VM(2); stage(3, kt + 2); }                  \
                else { WAIT_VM(0); }                                                  \
            }                                                                         \
            BARRIER();                                                                \
            WAIT_LGKM0();                                                             \
            __builtin_amdgcn_s_setprio(1);                                            \
            _Pragma("unroll")                                                         \
            for (int mi = 0; mi < 2; ++mi)                                            \
                _Pragma("unroll")                                                     \
                for (int n = 0; n < 4; ++n) {                                         \
                    acc[q * 2 + mi][n] = __builtin_amdgcn_mfma_f32_16x16x32_f16(      \
                        a[mi][0], b[n][0], acc[q * 2 + mi][n], 0, 0, 0);              \
                    acc[q * 2 + mi][n] = __builtin_amdgcn_mfma_f32_16x16x32_f16(      \
                        a[mi][1], b[n][1], acc[q * 2 + mi][n], 0, 0, 0);              \
                }                                                                     \
            __builtin_amdgcn_s_setprio(0);                                            \
            BARRIER();                                                                \
        }                                                                             \
    }

// ---- GEMM1 (xp @ wgu^T) + SwiGLU -> hidden; tail blocks convert wd -> wd16 ----
__global__ __launch_bounds__(512, 2) void k_gemm1(
    const f16* __restrict__ xp, const f16* __restrict__ wgu,
    const int* __restrict__ tile_map, f16* __restrict__ hidden,
    const float* __restrict__ wd, f16* __restrict__ wd16) {
    __shared__ char smem[131072];
    const int bid = blockIdx.x;
    if (bid >= G1TILES) {
        // tail-fold: wd fp32 -> f16 on CUs idle in GEMM1's last dispatch round
        const int cb = bid - G1TILES;                       // 0..127
        const int t = threadIdx.x;                          // 512
#pragma unroll 1
        for (int s = 0; s < 32; ++s) {
            const size_t i = ((size_t)s * CVT_BLKS + cb) * 512 + t;  // 8-elem chunks
            ((f16x8*)wd16)[i] = cvt8(wd + i * 8);
        }
        return;
    }
    const int ct = bid & 15, rt = bid >> 4;   // ct-fast
    const int e = tile_map[rt];
    if (e < 0) return;
    const int rbase = rt * 256, cbase = ct * 256;
    const f16* asrc = xp + (size_t)rbase * DMODEL;
    const f16* bsrc = wgu + (size_t)e * NGU * DMODEL + (size_t)cbase * DMODEL;

    GEMM_CORE(16, DMODEL)

    // epilogue: pair (gate,up) frags -> silu(g)*u -> hidden f16
#pragma unroll
    for (int mf = 0; mf < 8; ++mf) {
#pragma unroll
        for (int pair = 0; pair < 2; ++pair) {
            const int ng = pair * 2, nu = ng + 1;
            const int cblock = cbase + wn * 64 + ng * 16;   // bit4==0: gate
            const int h = ((cblock >> 5) << 4) + lrow;
#pragma unroll
            for (int r = 0; r < 4; ++r) {
                const int row = rbase + wm * 128 + mf * 16 + lk * 4 + r;
                const float gg = acc[mf][ng][r], uu = acc[mf][nu][r];
                const float hv = gg / (1.f + __expf(-gg)) * uu;
                hidden[(size_t)row * HDIM + h] = (f16)hv;
            }
        }
    }
}

// ======== GEMM2: 64x128 tiles, 4 waves, 48KB LDS (3 blocks/CU), 2-phase ========
// A (hidden) 64x64 dbuf 2x8KB; B (wd16) 128x64 dbuf 2x16KB. 6 gloads/wave/kt
// -> WAIT_VM(6) at top drains kt's tiles, keeps kt+1 in flight. ct==XCD.
// Wave tile 32r x 64c (2wm x 2wn); acc[2][4]; 16 MFMA/kt.
__global__ __launch_bounds__(256, 3) void k_gemm2(
    const f16* __restrict__ hidden, const f16* __restrict__ wd16,
    const int* __restrict__ tile_map64, const int* __restrict__ perm,
    float* __restrict__ out) {
    const int ct = blockIdx.x, rt = blockIdx.y;   // grid (8, 160); linear%8 = ct
    const int e = tile_map64[rt];
    if (e < 0) return;
    const int tid = threadIdx.x;
    const int lane = tid & 63, wid = tid >> 6;    // 4 waves
    const int wm = wid >> 1, wn = wid & 1;
    const int lrow = lane & 15, lk = lane >> 4;
    const int rbase = rt * 64, cbase = ct * 128;
    const f16* asrc = hidden + (size_t)rbase * HDIM;
    const f16* bsrc = wd16 + (size_t)e * DMODEL * HDIM + (size_t)cbase * HDIM;

    __shared__ char smem[49152];   // A dbuf 2x8KB @0, B dbuf 2x16KB @16384
    const int scol = (lane & 7) ^ (lane >> 3);

    auto stage2 = [&](int kt2) {
        char* dA = smem + (kt2 & 1) * 8192;
        char* dB = smem + 16384 + (kt2 & 1) * 16384;
        const int kb = kt2 * 64;
#pragma unroll
        for (int i = 0; i < 2; ++i) {                 // A: 8 chunks x 1KB (8 rows)
            const int chunk = wid * 2 + i;
            const int row = chunk * 8 + (lane >> 3);  // 0..63
            gload16(asrc + (size_t)row * HDIM + kb + scol * 8, dA + chunk * 1024);
        }
#pragma unroll
        for (int i = 0; i < 4; ++i) {                 // B: 16 chunks x 1KB
            const int chunk = wid * 4 + i;
            const int row = chunk * 8 + (lane >> 3);  // 0..127
            gload16(bsrc + (size_t)row * HDIM + kb + scol * 8, dB + chunk * 1024);
        }
    };

    int off_a[2][2], off_b[4][2];
#pragma unroll
    for (int f = 0; f < 2; ++f) {
        const int ra = wm * 32 + f * 16 + lrow;
#pragma unroll
        for (int kk = 0; kk < 2; ++kk)
            off_a[f][kk] = ra * 128 + (((kk * 4 + lk) ^ (ra & 7)) * 16);
    }
#pragma unroll
    for (int n = 0; n < 4; ++n) {
        const int rb = wn * 64 + n * 16 + lrow;
#pragma unroll
        for (int kk = 0; kk < 2; ++kk)
            off_b[n][kk] = rb * 128 + (((kk * 4 + lk) ^ (rb & 7)) * 16);
    }

    f32x4 acc[2][4] = {};
    stage2(0);
    _Pragma("unroll 1")
    for (int kt = 0; kt < 32; ++kt) {
        if (kt + 1 < 32) { stage2(kt + 1); WAIT_VM(6); }
        else { WAIT_VM(0); }
        BARRIER();                        // kt tiles resident for all waves
        char* bA = smem + (kt & 1) * 8192;
        char* bB = smem + 16384 + (kt & 1) * 16384;
        f16x8 a[2][2], b[4][2];
#pragma unroll
        for (int f = 0; f < 2; ++f)
#pragma unroll
            for (int kk = 0; kk < 2; ++kk)
                a[f][kk] = *(const f16x8*)(bA + off_a[f][kk]);
#pragma unroll
        for (int n = 0; n < 4; ++n)
#pragma unroll
            for (int kk = 0; kk < 2; ++kk)
                b[n][kk] = *(const f16x8*)(bB + off_b[n][kk]);
        WAIT_LGKM0();
        __builtin_amdgcn_s_setprio(1);
#pragma unroll
        for (int m = 0; m < 2; ++m)
#pragma unroll
            for (int n = 0; n < 4; ++n) {
                acc[m][n] = __builtin_amdgcn_mfma_f32_16x16x32_f16(a[m][0], b[n][0], acc[m][n], 0, 0, 0);
                acc[m][n] = __builtin_amdgcn_mfma_f32_16x16x32_f16(a[m][1], b[n][1], acc[m][n], 0, 0, 0);
            }
        __builtin_amdgcn_s_setprio(0);
        BARRIER();                        // reads done before next overwrite
    }

    // epilogue: direct scatter to token rows (fp32)
#pragma unroll
    for (int mf = 0; mf < 2; ++mf) {
        int toks[4];
#pragma unroll
        for (int r = 0; r < 4; ++r)
            toks[r] = perm[rbase + wm * 32 + mf * 16 + lk * 4 + r];
#pragma unroll
        for (int n = 0; n < 4; ++n) {
            const int col = cbase + wn * 64 + n * 16 + lrow;
#pragma unroll
            for (int r = 0; r < 4; ++r)
                if (toks[r] >= 0) out[(size_t)toks[r] * DMODEL + col] = acc[mf][n][r];
        }
    }
}

extern "C" void kernel_launch(void* const* d_in, const int* in_sizes, int n_in,
                              void* d_out, int out_size, void* d_ws, size_t ws_size,
                              hipStream_t stream) {
    const float* x = (const float*)d_in[0];
    const float* wg = (const float*)d_in[1];
    const float* wu = (const float*)d_in[2];
    const float* wd = (const float*)d_in[3];
    const int* ids = (const int*)d_in[4];
    float* out = (float*)d_out;

    char* ws = (char*)d_ws;
    int* cursor = (int*)ws;
    int* tile_map = (int*)(ws + 64);
    int* tile_map64 = (int*)(ws + 512);
    int* perm = (int*)(ws + 4096);
    const size_t XP_OFF = 65536;
    const size_t XP_BYTES = (size_t)NPAD * DMODEL * 2;          // 21.0 MB
    const size_t HID_OFF = XP_OFF + XP_BYTES;
    const size_t HID_BYTES = (size_t)NPAD * HDIM * 2;           // 41.9 MB
    const size_t WGU_OFF = HID_OFF + HID_BYTES;
    const size_t WGU_BYTES = (size_t)NEXP * NGU * DMODEL * 2;   // 67.1 MB
    const size_t WD_OFF = WGU_OFF + WGU_BYTES;
    const size_t WD_BYTES = (size_t)NEXP * DMODEL * HDIM * 2;   // 33.6 MB
    const bool big_ws = ws_size >= WD_OFF + WD_BYTES;           // ~163.7 MB

    f16* xp = (f16*)(ws + XP_OFF);
    f16* hidden = (f16*)(ws + HID_OFF);
    f16* wgu16 = (f16*)(ws + WGU_OFF);
    f16* wd16 = big_ws ? (f16*)(ws + WD_OFF) : (f16*)(ws + WGU_OFF);

    k_plan<<<1, 256, 0, stream>>>(ids, cursor, tile_map, tile_map64, perm);
    k_scatter<<<N_TOK / 256, 256, 0, stream>>>(ids, cursor, perm);
    k_prep<<<NPAD + NEXP * NGU, 128, 0, stream>>>(x, perm, xp, wg, wu, wgu16);
    if (big_ws) {
        k_gemm1<<<G1TILES + CVT_BLKS, 512, 0, stream>>>(xp, wgu16, tile_map, hidden, wd, wd16);
    } else {
        k_gemm1<<<G1TILES, 512, 0, stream>>>(xp, wgu16, tile_map, hidden, wd, wd16);
        k_cvt<<<8192, 256, 0, stream>>>(wd, wd16);
    }
    k_gemm2<<<dim3(8, NT64), 256, 0, stream>>>(hidden, wd16, tile_map64, perm, out);
}